// Round 12
// baseline (516.155 us; speedup 1.0000x reference)
//
#include <hip/hip_runtime.h>

// LSTM discriminator: B=2048, T=1024, I=4, H=16, gates 4H=64.
// R12: STOP fighting the register allocator (R7/R8/R9: pins + launch_bounds
// all null, VGPR stuck at 24-28, ~2x instr bloat from spill/reload traffic).
// Instead design for a ~32-VGPR budget: weights STREAM from LDS each step.
//  - Init: lane l writes its W_hh row to LDS pre-permuted into the XOR-tree
//    consumption order CONS=[0,1,2,3,7,6,5,4,15,14,13,12,8,9,10,11] and
//    chunk-rotated by rot=(l>>3)&3 (row stride 80B, 16B-aligned slots).
//    Bank math: lanes d apart, d=1..7: base 20d mod 32 gives disjoint 4-bank
//    windows; d=8,16,24: same base, different rot -> disjoint slots; d=32:
//    same address -> broadcast. ds_read_b128 is conflict-free.
//  - Per step: 4x ds_read_b128, addresses PINNED per-iteration via null asm
//    ("+v") so LICM can't hoist the loads (values then live only load->FMA,
//    nothing for the allocator to spill).
//  - DPP broadcast tree + x-proj run in parallel with the LDS latency;
//    2 waves/SIMD (2048 blocks x 1 wave) cover the rest.
// Lane l owns gate row l (0-15=i,16-31=f,32-47=g,48-63=o), j=l&15; every
// lane holds h_{l&15}. Gate gather: swz16 / permlane32_swap (R6-verified:
// hi lanes take pr[0], lo pr[1]) / swz16. Readout: DPP tree, no LDS.

#define T_DIM 1024
#define LOG2E 1.4426950408889634f

typedef __attribute__((ext_vector_type(2))) int i32x2;

__device__ __forceinline__ float fsig(float x) {
    float e = __builtin_amdgcn_exp2f(-x * LOG2E);
    return __builtin_amdgcn_rcpf(1.0f + e);
}

template<int CTRL>
__device__ __forceinline__ float dpp_f(float v) {
    int i = __float_as_int(v);
    return __int_as_float(__builtin_amdgcn_update_dpp(i, i, CTRL, 0xF, 0xF, false));
}
// quad_perm xor1=0xB1, xor2=0x4E, xor3=0x1B; ROW_HALF_MIRROR=0x141 (j^7),
// ROW_MIRROR=0x140 (j^15); ROW_ROR:4=0x124, ROW_ROR:8=0x128.

__device__ __forceinline__ float swz16(float v) {
    // ds_swizzle BitMode xor=16: lane l <-> l^16 within each 32-group
    return __int_as_float(__builtin_amdgcn_ds_swizzle(__float_as_int(v), 0x401F));
}

__device__ __forceinline__ float xchg32(float v, bool hi32) {
#if __has_builtin(__builtin_amdgcn_permlane32_swap)
    i32x2 pr = __builtin_amdgcn_permlane32_swap(__float_as_int(v), __float_as_int(v), false, false);
    // vdst.hi <-> vsrc.lo: pr[0]={lo,lo}, pr[1]={hi,hi}; hi lanes want lo data
    return __int_as_float(hi32 ? pr[0] : pr[1]);
#else
    int l = threadIdx.x & 63;
    return __int_as_float(__builtin_amdgcn_ds_bpermute(((l ^ 32) << 2), __float_as_int(v)));
#endif
}

__global__ __launch_bounds__(64, 2) void lstm_disc_kernel(
    const float* __restrict__ x,      // [B, T, 4]
    const float* __restrict__ W_ih,   // [64, 4]
    const float* __restrict__ W_hh,   // [64, 16]
    const float* __restrict__ b_ih,   // [64]
    const float* __restrict__ b_hh,   // [64]
    const float* __restrict__ W_d,    // [1, 16]
    const float* __restrict__ b_d,    // [1]
    float* __restrict__ out)          // [B, T]
{
    const int l  = threadIdx.x;          // gate row
    const int j  = l & 15;               // hidden index
    const bool s1 = (l & 16) != 0;
    const bool s2 = (l & 32) != 0;
    const int batch = blockIdx.x;        // 1 sequence per wave

    __shared__ __align__(16) float wlds[64 * 20];   // 5 KiB: 16 dw data + 4 dw pad/row

    // ---- init: permuted + chunk-rotated weight row into LDS ----
    const int CONS[16] = {0,1,2,3, 7,6,5,4, 15,14,13,12, 8,9,10,11};
    const int rot = (l >> 3) & 3;
#pragma unroll
    for (int k = 0; k < 4; ++k) {
        const int slot = (k + rot) & 3;
#pragma unroll
        for (int e = 0; e < 4; ++e)
            wlds[l * 20 + slot * 4 + e] = W_hh[l * 16 + (j ^ CONS[k * 4 + e])];
    }
    __syncthreads();

    // chunk byte addresses (loop-invariant; pinned per-iter against LICM)
    unsigned A0 = (unsigned)(l * 80 + ((0 + rot) & 3) * 16);
    unsigned A1 = (unsigned)(l * 80 + ((1 + rot) & 3) * 16);
    unsigned A2 = (unsigned)(l * 80 + ((2 + rot) & 3) * 16);
    unsigned A3 = (unsigned)(l * 80 + ((3 + rot) & 3) * 16);
    const char* wb = (const char*)&wlds[0];

    float4 Wx = *reinterpret_cast<const float4*>(W_ih + l * 4);
    float bias = b_ih[l] + b_hh[l];
    float wd = W_d[j];
    float bd = b_d[0];
    asm volatile("" : "+v"(Wx.x), "+v"(Wx.y), "+v"(Wx.z), "+v"(Wx.w));
    asm volatile("" : "+v"(bias), "+v"(wd), "+v"(bd));
    const bool isg = s2 && !s1;            // g-rows: tanh
    const float m2  = isg ? 2.0f : 1.0f;   // act = m*sig(m*x) - (m-1)
    const float m2n = isg ? -1.0f : 0.0f;

    const float4* xp = reinterpret_cast<const float4*>(x + (size_t)batch * (T_DIM * 4));
    float4 xv = xp[0];

    float h = 0.0f, c = 0.0f;
    float s0v = 0.f, s1v = 0.f, s2v = 0.f;

    for (int t4 = 0; t4 < T_DIM; t4 += 4) {
#pragma unroll
        for (int u = 0; u < 4; ++u) {
            const int t = t4 + u;
            const float4 xn = xp[(t + 1 < T_DIM) ? (t + 1) : (T_DIM - 1)];

            // pin addresses (new SSA value each iter -> loads can't be hoisted)
            asm volatile("" : "+v"(A0), "+v"(A1), "+v"(A2), "+v"(A3));
            const float4 w0 = *reinterpret_cast<const float4*>(wb + A0);
            const float4 w1 = *reinterpret_cast<const float4*>(wb + A1);
            const float4 w2 = *reinterpret_cast<const float4*>(wb + A2);
            const float4 w3 = *reinterpret_cast<const float4*>(wb + A3);

            // x-projection (independent of h and of the LDS reads)
            const float gx = fmaf(Wx.x, xv.x, fmaf(Wx.y, xv.y,
                               fmaf(Wx.z, xv.z, fmaf(Wx.w, xv.w, bias))));

            // ---- XOR-tree broadcast of h, consuming weight chunks in order ----
            const float v1 = dpp_f<0xB1>(h);      // j^1
            const float v2 = dpp_f<0x4E>(h);      // j^2
            const float v3 = dpp_f<0x1B>(h);      // j^3
            float a0 = fmaf(w0.x, h, gx);
            float a1 = w0.y * v1;
            float a2 = w0.z * v2;
            float a3 = w0.w * v3;
            const float m7 = dpp_f<0x141>(h);     // j^7
            const float mF = dpp_f<0x140>(h);     // j^15
            const float v6 = dpp_f<0xB1>(m7);     // j^6
            const float v5 = dpp_f<0x4E>(m7);     // j^5
            const float v4 = dpp_f<0x1B>(m7);     // j^4
            a0 = fmaf(w1.x, m7, a0);
            a1 = fmaf(w1.y, v6, a1);
            a2 = fmaf(w1.z, v5, a2);
            a3 = fmaf(w1.w, v4, a3);
            const float vE = dpp_f<0xB1>(mF);     // j^14
            const float vD = dpp_f<0x4E>(mF);     // j^13
            const float vC = dpp_f<0x1B>(mF);     // j^12
            const float m8 = dpp_f<0x141>(mF);    // j^8
            a0 = fmaf(w2.x, mF, a0);
            a1 = fmaf(w2.y, vE, a1);
            a2 = fmaf(w2.z, vD, a2);
            a3 = fmaf(w2.w, vC, a3);
            const float v9 = dpp_f<0xB1>(m8);     // j^9
            const float vA = dpp_f<0x4E>(m8);     // j^10
            const float vB = dpp_f<0x1B>(m8);     // j^11
            a0 = fmaf(w3.x, m8, a0);
            a1 = fmaf(w3.y, v9, a1);
            a2 = fmaf(w3.z, vA, a2);
            a3 = fmaf(w3.w, vB, a3);
            const float g = (a0 + a1) + (a2 + a3);

            // ---- own gate activation ----
            const float act = fmaf(m2, fsig(m2 * g), m2n);

            // ---- 4-way gather of (i,f,g,o) ----
            const float b16 = swz16(act);
            const float b32 = xchg32(act, s2);
            const float b48 = swz16(b32);
            const float pa = s1 ? b16 : act;       // i
            const float pb = s1 ? b48 : b32;       // g
            const float ig = pa * pb;
            const float f1 = s2 ? b48 : b16;
            const float f2 = s2 ? b32 : act;
            const float fg = s1 ? f2 : f1;         // f
            const float o1 = s2 ? b16 : b48;
            const float o2 = s2 ? act : b32;
            const float og = s1 ? o2 : o1;         // o

            // ---- cell update ----
            c = fmaf(fg, c, ig);
            const float tc = fmaf(2.0f, fsig(2.0f * c), -1.0f);   // tanh(c)
            h = og * tc;

            // ---- readout: dot(h, W_d) via DPP tree ----
            float p = h * wd;
            p += dpp_f<0xB1>(p);
            p += dpp_f<0x4E>(p);
            p += dpp_f<0x124>(p);                  // ror4
            p += dpp_f<0x128>(p);                  // ror8
            const float oo = fsig(p + bd);

            if (u == 0) s0v = oo;
            else if (u == 1) s1v = oo;
            else if (u == 2) s2v = oo;
            else if (l == 0)
                *reinterpret_cast<float4*>(out + (size_t)batch * T_DIM + t4) =
                    make_float4(s0v, s1v, s2v, oo);

            xv = xn;
        }
    }
}

extern "C" void kernel_launch(void* const* d_in, const int* in_sizes, int n_in,
                              void* d_out, int out_size, void* d_ws, size_t ws_size,
                              hipStream_t stream) {
    const float* x    = (const float*)d_in[0];
    const float* W_ih = (const float*)d_in[1];
    const float* W_hh = (const float*)d_in[2];
    const float* b_ih = (const float*)d_in[3];
    const float* b_hh = (const float*)d_in[4];
    const float* W_d  = (const float*)d_in[5];
    const float* b_d  = (const float*)d_in[6];
    float* out = (float*)d_out;

    // 2048 blocks x 1 wave = 2 waves/SIMD machine-wide
    lstm_disc_kernel<<<2048, 64, 0, stream>>>(x, W_ih, W_hh, b_ih, b_hh, W_d, b_d, out);
}